// Round 12
// baseline (88.841 us; speedup 1.0000x reference)
//
#include <hip/hip_runtime.h>
#include <math.h>

// GptOssTopKRouter on MI355X — round 12: burst-staged X + 32x32x16 split-bf16 MFMA.
//
// r7-r11 all pin at 52-56us (4 nulls across schedule variants) => the invariant
// is DRAM burst granularity: 16384 concurrent row-streams advancing 64B/request
// halves HBM efficiency (3.4 of 6.3 TB/s). Fix: cooperative row-major staging —
// each global_load_dwordx4 instruction reads ONE token-row's contiguous 768B
// chunk (12x larger bursts), LDS-tiled with XOR swizzle, double-buffered with
// ONE raw barrier per chunk and compiler-counted vmcnt.
//
// Compute (verified r7-r11): logits^T = W[32,2880] @ X^T, 6 bf16 MFMA passes
// of 3-term trunc split (hh,mh,lh,hm,mm,hl; logit err ~2e-7, tie-safe top-4).
// 32x32x16: 32 experts = one A-tile (W pre-split fragment-packed in d_ws),
// 32 tokens = one B-tile; B-frag col=lane&31=token, k=(lane>>5)*8+j read from
// the swizzled LDS tile, split to bf16 in registers.
// Block = 32 tokens, 8 waves; chunk = 192 floats (12 k16-steps, 15 chunks,
// no padding: 2880 = 15*192); step s of chunk c runs on wave (s+... rotation
// sl0=(w+4c)&7 balances 12 steps over 8 waves. 48 KB LDS -> 2 blocks/CU.

#define HIDDEN 2880
#define NE 32
#define TOPK 4
#define TPB 32            // tokens per block
#define CKF 192           // floats per chunk per row
#define SPC 12            // k16-steps per chunk
#define NCH 15            // chunks (15*192 = 2880 exactly)
#define NK16 180          // total k16 steps
#define VS (NK16 * 512)   // ver stride in wb: 92160 shorts

typedef __attribute__((ext_vector_type(8)))  short bf16x8;
typedef __attribute__((ext_vector_type(16))) float f32x16;

#define MFMA32(a, b, c) __builtin_amdgcn_mfma_f32_32x32x16_bf16((a), (b), (c), 0, 0, 0)

// Pre-kernel: W[32][2880] fp32 -> WB[3 ver][180 ks][512] bf16, exact 32x32
// A-fragment order: elem (l,j) = split_ver(W[l&31][ks*16 + (l>>5)*8 + j]).
__global__ void wb_kernel(const float* __restrict__ w, unsigned short* __restrict__ wb) {
    int i = blockIdx.x * 256 + threadIdx.x;
    if (i >= 3 * VS) return;
    int j = i & 7;
    int l = (i >> 3) & 63;
    int rest = i >> 9;
    int ks  = rest % NK16;
    int ver = rest / NK16;
    int e = l & 31;
    int k = ks * 16 + (l >> 5) * 8 + j;
    float v = w[e * HIDDEN + k];
    unsigned u = __float_as_uint(v);
    unsigned h = u >> 16;
    float r = v - __uint_as_float(u & 0xffff0000u);          // exact
    unsigned ur = __float_as_uint(r);
    unsigned m = ur >> 16;
    float r2 = r - __uint_as_float(ur & 0xffff0000u);        // exact
    unsigned lo = __float_as_uint(r2) >> 16;
    wb[i] = (unsigned short)(ver == 0 ? h : (ver == 1 ? m : lo));
}

// split 8 consecutive fp32 -> 3 bf16x8 (hi, mid, lo), fully in-register
__device__ __forceinline__ void split24(float4 a, float4 b,
                                        bf16x8& H, bf16x8& M, bf16x8& L) {
    union { bf16x8 v; unsigned u[4]; } h, m, l;
    float f[8] = {a.x, a.y, a.z, a.w, b.x, b.y, b.z, b.w};
    unsigned hh[8], mm[8], ll[8];
#pragma unroll
    for (int i = 0; i < 8; ++i) {
        unsigned u = __float_as_uint(f[i]);
        hh[i] = u >> 16;
        float r = f[i] - __uint_as_float(u & 0xffff0000u);   // exact
        unsigned ur = __float_as_uint(r);
        mm[i] = ur >> 16;
        float r2 = r - __uint_as_float(ur & 0xffff0000u);    // exact
        ll[i] = __float_as_uint(r2) >> 16;
    }
#pragma unroll
    for (int i = 0; i < 4; ++i) {
        h.u[i] = hh[2 * i] | (hh[2 * i + 1] << 16);
        m.u[i] = mm[2 * i] | (mm[2 * i + 1] << 16);
        l.u[i] = ll[2 * i] | (ll[2 * i + 1] << 16);
    }
    H = h.v; M = m.v; L = l.v;
}

__global__ __launch_bounds__(512, 4)
void router_kernel(const float* __restrict__ x,
                   const unsigned short* __restrict__ wb,
                   const float* __restrict__ bias,
                   float* __restrict__ out_scores,
                   float* __restrict__ out_idx)
{
    __shared__ float pool[2 * TPB * CKF];     // 48 KB; epilogue overlays it
    float* buf0 = pool;
    float* buf1 = pool + TPB * CKF;

    const int tid  = threadIdx.x;
    const int lane = tid & 63;
    const int w    = tid >> 6;
    const int col  = lane & 31;       // token (= B-frag col)
    const int kg   = lane >> 5;       // frag k group
    const int tok0 = blockIdx.x * TPB;

    // ---- staging geometry: 3 float4s/thread/chunk; consecutive lanes cover
    //      one row's contiguous 768B (row-major burst order) ----
    const float* xg[3];
    int wi[3];
#pragma unroll
    for (int i = 0; i < 3; ++i) {
        int f    = i * 512 + tid;          // 0..1535 over [32 rows][48 slots]
        int grow = f / 48;
        int gcol = f - grow * 48;
        xg[i] = x + (size_t)(tok0 + grow) * HIDDEN + gcol * 4;
        wi[i] = grow * CKF + ((gcol ^ (grow & 15)) << 2);    // XOR-swizzled dest
    }

    const int rbase = col * CKF;
    const int rx    = col & 15;            // read-side swizzle key
    const unsigned short* wk = wb + lane * 8;

    f32x16 acc = {0.f};
    float4 gA[3], gB[3];

#define GLOAD(g, c) do { _Pragma("unroll")                                        \
    for (int i_ = 0; i_ < 3; ++i_)                                                \
        g[i_] = *(const float4*)(xg[i_] + (size_t)(c) * CKF);                     \
} while (0)

#define SWRITE(dst, g) do { _Pragma("unroll")                                     \
    for (int i_ = 0; i_ < 3; ++i_)                                                \
        *(float4*)((dst) + wi[i_]) = g[i_];                                       \
} while (0)

#define BARW() do {                                                               \
    asm volatile("s_waitcnt lgkmcnt(0)" ::: "memory");                            \
    __builtin_amdgcn_s_barrier();                                                 \
    asm volatile("" ::: "memory");                                                \
} while (0)

#define MFMA6(WH, WM, WL, XH, XM, XL) do {                                        \
    acc = MFMA32(WH, XH, acc);                                                    \
    acc = MFMA32(WM, XH, acc);                                                    \
    acc = MFMA32(WL, XH, acc);                                                    \
    acc = MFMA32(WH, XM, acc);                                                    \
    acc = MFMA32(WM, XM, acc);                                                    \
    acc = MFMA32(WH, XL, acc);                                                    \
} while (0)

// wave w handles step sl0=(w+4c)&7 of chunk c, plus sl0+8 if sl0<4 (12 steps/8 waves)
#define COMPUTE(buf, c) do {                                                      \
    const int sl0_ = (w + 4 * (c)) & 7;                                           \
    const int g0_  = (c) * SPC + sl0_;                                            \
    const bool two_ = sl0_ < 4;                                                   \
    const unsigned short* p0_ = wk + (size_t)g0_ * 512;                           \
    bf16x8 W0h = *(const bf16x8*)(p0_);                                           \
    bf16x8 W0m = *(const bf16x8*)(p0_ + VS);                                      \
    bf16x8 W0l = *(const bf16x8*)(p0_ + 2 * VS);                                  \
    const int sA_ = sl0_ * 4 + kg * 2;                                            \
    float4 a0_ = *(const float4*)((buf) + rbase + ((sA_)     ^ rx) * 4);          \
    float4 a1_ = *(const float4*)((buf) + rbase + ((sA_ + 1) ^ rx) * 4);          \
    if (two_) {                                                                   \
        const unsigned short* p1_ = p0_ + 8 * 512;                                \
        bf16x8 W1h = *(const bf16x8*)(p1_);                                       \
        bf16x8 W1m = *(const bf16x8*)(p1_ + VS);                                  \
        bf16x8 W1l = *(const bf16x8*)(p1_ + 2 * VS);                              \
        const int sB_ = sA_ + 32;                                                 \
        float4 b0_ = *(const float4*)((buf) + rbase + ((sB_)     ^ rx) * 4);      \
        float4 b1_ = *(const float4*)((buf) + rbase + ((sB_ + 1) ^ rx) * 4);      \
        bf16x8 xh_, xm_, xl_;                                                     \
        split24(a0_, a1_, xh_, xm_, xl_);                                         \
        MFMA6(W0h, W0m, W0l, xh_, xm_, xl_);                                      \
        split24(b0_, b1_, xh_, xm_, xl_);                                         \
        MFMA6(W1h, W1m, W1l, xh_, xm_, xl_);                                      \
    } else {                                                                      \
        bf16x8 xh_, xm_, xl_;                                                     \
        split24(a0_, a1_, xh_, xm_, xl_);                                         \
        MFMA6(W0h, W0m, W0l, xh_, xm_, xl_);                                      \
    }                                                                             \
} while (0)

    // prologue: buf0 <- chunk0; gB holds chunk1; gA reloaded with chunk2
    GLOAD(gA, 0);
    GLOAD(gB, 1);
    SWRITE(buf0, gA);                     // compiler inserts counted vmcnt
    GLOAD(gA, 2);
    BARW();

#pragma unroll 1
    for (int cc = 0; cc < 7; ++cc) {      // chunks 0..13
        const int c0 = 2 * cc;
        COMPUTE(buf0, c0);
        SWRITE(buf1, gB);                 // chunk c0+1 (read of buf1 was pre-barrier last iter)
        if (cc < 6) GLOAD(gB, c0 + 3);
        BARW();
        COMPUTE(buf1, c0 + 1);
        SWRITE(buf0, gA);                 // chunk c0+2
        if (cc < 6) GLOAD(gA, c0 + 4);
        BARW();
    }
    COMPUTE(buf0, 14);                    // final chunk
    __syncthreads();

#undef GLOAD
#undef SWRITE
#undef BARW
#undef MFMA6
#undef COMPUTE

    // ---- epilogue (overlays pool): C/D layout (m74/m101): col=lane&31=token,
    //      row=(reg&3)+8*(reg>>2)+4*kg = expert ----
    float (*part)[TPB][36] = (float (*)[TPB][36])pool;        // 8*32*36 = 9216 floats
    float (*score)[33]     = (float (*)[33])(pool + 9216);    // 1056 floats

#pragma unroll
    for (int r = 0; r < 16; ++r)
        part[w][col][(r & 3) + 8 * (r >> 2) + 4 * kg] = acc[r];
    __syncthreads();

    if (tid < TPB) {
        float lg[NE];
#pragma unroll
        for (int e = 0; e < NE; ++e) {
            float s = bias[e];
#pragma unroll
            for (int p = 0; p < 8; ++p) s += part[p][tid][e];
            lg[e] = s;
        }

        float vals[TOPK]; int idxs[TOPK]; unsigned chosen = 0u;
#pragma unroll
        for (int k = 0; k < TOPK; ++k) {
            float m = -INFINITY; int mi = 0;
#pragma unroll
            for (int e = 0; e < NE; ++e) {
                const bool take = (((chosen >> e) & 1u) == 0u) && (lg[e] > m);
                m  = take ? lg[e] : m;
                mi = take ? e : mi;
            }
            vals[k] = m; idxs[k] = mi; chosen |= (1u << (unsigned)mi);
        }
        const float mx = vals[0];
        float p[TOPK]; float sum = 0.f;
#pragma unroll
        for (int k = 0; k < TOPK; ++k) { p[k] = __expf(vals[k] - mx); sum += p[k]; }
        const float inv = 1.0f / sum;
#pragma unroll
        for (int e = 0; e < NE; ++e) {
            float v = 0.f;
#pragma unroll
            for (int k = 0; k < TOPK; ++k) v = (e == idxs[k]) ? p[k] * inv : v;
            score[tid][e] = v;
        }
        const int t = blockIdx.x * TPB + tid;
        float4 iv = make_float4((float)idxs[0], (float)idxs[1], (float)idxs[2], (float)idxs[3]);
        *reinterpret_cast<float4*>(out_idx + (size_t)t * TOPK) = iv;
    }
    __syncthreads();

    // coalesced score store: 1024 floats, 512 threads x float2
    {
        const int f = tid * 2;
        const int t = f >> 5, e = f & 31;
        float2 v = make_float2(score[t][e], score[t][e + 1]);
        *reinterpret_cast<float2*>(out_scores + (size_t)blockIdx.x * TPB * NE + f) = v;
    }
}

extern "C" void kernel_launch(void* const* d_in, const int* in_sizes, int n_in,
                              void* d_out, int out_size, void* d_ws, size_t ws_size,
                              hipStream_t stream)
{
    const float* x = (const float*)d_in[0];
    const float* w = (const float*)d_in[1];
    const float* b = (const float*)d_in[2];
    const int T = in_sizes[0] / HIDDEN;            // 16384 tokens

    unsigned short* wbuf = (unsigned short*)d_ws;  // 3*180*512 bf16 = 553 KB
    float* out        = (float*)d_out;
    float* out_scores = out;                       // [T, 32]
    float* out_idx    = out + (size_t)T * NE;      // [T, 4] as fp32 values

    wb_kernel<<<dim3((3 * VS + 255) / 256), dim3(256), 0, stream>>>(w, wbuf);
    router_kernel<<<dim3(T / TPB), dim3(512), 0, stream>>>(x, wbuf, b, out_scores, out_idx);
}